// Round 1
// baseline (746.939 us; speedup 1.0000x reference)
//
#include <hip/hip_runtime.h>
#include <math.h>

#define NL    64
#define NOBS  400
#define NC    3000
#define BPT   4            // blocks per T-observation
#define CPB   (NC / BPT)   // 750 C-values per block
#define TWO_PI_F 6.2831853071795864769f
#define LOG2_0P1 -3.3219280948873623f

// ---------------------------------------------------------------------------
// Kernel 1: Brocher relations  b -> (a, rho), stored to workspace
// ---------------------------------------------------------------------------
__global__ void prep_kernel(const float* __restrict__ b, float* __restrict__ a_out,
                            float* __restrict__ rho_out) {
    int i = threadIdx.x;
    if (i < NL) {
        float bb = b[i];
        float b2 = bb * bb, b3 = b2 * bb, b4 = b3 * bb;
        float a = 0.9409f + 2.0947f * bb - 0.8206f * b2 + 0.2683f * b3 - 0.0251f * b4;
        float a2 = a * a, a3 = a2 * a, a4 = a3 * a, a5 = a4 * a;
        float rho = 1.6612f * a - 0.4721f * a2 + 0.0671f * a3 - 0.0043f * a4 + 0.000106f * a5;
        a_out[i] = a;
        rho_out[i] = rho;
    }
}

// ---------------------------------------------------------------------------
// Per-layer block-uniform precomputed parameters (omega fixed per block)
// ---------------------------------------------------------------------------
struct LayerShared {
    float xka[NL];
    float xkb[NL];
    float gammk[NL];
    float dm[NL];
    float rm[NL];
    float irm[NL];
    float rho2[NL];
    float irho2[NL];
};

// Dunkin determinant evaluation for one (cvel, omega) pair.
__device__ __forceinline__ float det_eval(float cvel, float omega, const LayerShared& L) {
    float wvno  = omega / cvel;
    float wvno2 = wvno * wvno;

    // halfspace (layer NL-1)
    float xka = L.xka[NL - 1];
    float xkb = L.xkb[NL - 1];
    float ra  = sqrtf((wvno + xka) * fabsf(wvno - xka));
    float rb  = sqrtf((wvno + xkb) * fabsf(wvno - xkb));
    float gammk = L.gammk[NL - 1];
    float gam   = gammk * wvno2;
    float gamm1 = gam - 1.0f;
    float r     = L.rm[NL - 1];
    float rarb  = ra * rb;

    float e0 = r * r * (gamm1 * gamm1 - gam * gammk * rarb);
    float e1 = -r * ra;
    float e2 = r * (gamm1 - gammk * rarb);
    float e3 = r * rb;
    float e4 = wvno2 - rarb;

    for (int m = NL - 2; m >= 0; --m) {
        xka = L.xka[m];
        xkb = L.xkb[m];
        ra  = sqrtf((wvno + xka) * fabsf(wvno - xka));
        rb  = sqrtf((wvno + xkb) * fabsf(wvno - xkb));
        gammk = L.gammk[m];
        gam   = gammk * wvno2;
        float dm = L.dm[m];
        float p = ra * dm;
        float q = rb * dm;

        // ---- _var ----
        float ra_s = (ra > 0.0f) ? ra : 1.0f;
        float rb_s = (rb > 0.0f) ? rb : 1.0f;

        float sinp = sinf(p);
        float facp = (p < 16.0f) ? expf(-2.0f * p) : 0.0f;
        float sinp_e = (1.0f - facp) * 0.5f;
        bool ltp = wvno < xka;
        bool eqp = wvno == xka;
        float pex  = (ltp || eqp) ? 0.0f : p;
        float cosp = ltp ? cosf(p) : (eqp ? 1.0f : (1.0f + facp) * 0.5f);
        float w = ltp ? (sinp / ra_s) : (eqp ? dm : (sinp_e / ra_s));
        float x = ltp ? (-ra * sinp) : (eqp ? 0.0f : (ra * sinp_e));

        float sinq = sinf(q);
        float facq = (q < 16.0f) ? expf(-2.0f * q) : 0.0f;
        float sinq_e = (1.0f - facq) * 0.5f;
        bool lts = wvno < xkb;
        bool eqs = wvno == xkb;
        float sex  = (lts || eqs) ? 0.0f : q;
        float cosq = lts ? cosf(q) : (eqs ? 1.0f : (1.0f + facq) * 0.5f);
        float y = lts ? (sinq / rb_s) : (eqs ? dm : (sinq_e / rb_s));
        float z = lts ? (-rb * sinq) : (eqs ? 0.0f : (rb * sinq_e));

        float exa = pex + sex;
        float a0  = (exa < 60.0f) ? expf(-exa) : 0.0f;

        float cpcq = cosp * cosq;
        float cpy  = cosp * y,  cpz = cosp * z;
        float cqw  = cosq * w,  cqx = cosq * x;
        float xy = x * y, xz = x * z, wy = w * y, wz = w * z;

        // ---- ca entries ----
        float gamm1l = gam - 1.0f;
        float twgm1  = gam + gamm1l;
        float gmgmk  = gam * gammk;
        float gmgm1  = gam * gamm1l;
        float gm1sq  = gamm1l * gamm1l;
        float rm    = L.rm[m];
        float irm   = L.irm[m];
        float rho2  = L.rho2[m];
        float irho2 = L.irho2[m];
        float a0pq = a0 - cpcq;
        float t2   = -2.0f * wvno2;

        float c00 = cpcq - 2.0f * gmgm1 * a0pq - gmgmk * xz - wvno2 * gm1sq * wy;
        float c01 = (wvno2 * cpy - cqx) * irm;
        float c02 = -(twgm1 * a0pq + gammk * xz + wvno2 * gamm1l * wy) * irm;
        float c03 = (cpz - wvno2 * cqw) * irm;
        float c04 = -(2.0f * wvno2 * a0pq + xz + wvno2 * wvno2 * wy) * irho2;
        float c10 = (gmgmk * cpz - gm1sq * cqw) * rm;
        float c12 = gammk * cpz - gamm1l * cqw;
        float c30 = (gm1sq * cpy - gmgmk * cqx) * rm;
        float c32 = gamm1l * cpy - gammk * cqx;
        float c40 = -(2.0f * gmgmk * gm1sq * a0pq + gmgmk * gmgmk * xz + gm1sq * gm1sq * wy) * rho2;
        float c42 = -(gmgm1 * twgm1 * a0pq + gam * gammk * gammk * xz + gamm1l * gm1sq * wy) * rm;
        float c22 = a0 + 2.0f * (cpcq - c00);
        float c20 = t2 * c42;
        float c21 = t2 * c32;
        float c23 = t2 * c12;
        float c24 = t2 * c02;

        // ee[i] = sum_j e[j] * ca[j][i]   (c11=c33=cpcq, c13=-wz, c31=-xy,
        //  c14=c03, c34=c01, c41=c30, c43=c10, c44=c00)
        float ee0 = e0 * c00 + e1 * c10 + e2 * c20 + e3 * c30 + e4 * c40;
        float ee1 = e0 * c01 + e1 * cpcq + e2 * c21 - e3 * xy  + e4 * c30;
        float ee2 = e0 * c02 + e1 * c12  + e2 * c22 + e3 * c32 + e4 * c42;
        float ee3 = e0 * c03 - e1 * wz   + e2 * c23 + e3 * cpcq + e4 * c10;
        float ee4 = e0 * c04 + e1 * c03  + e2 * c24 + e3 * c01 + e4 * c00;

        float nrm = fmaxf(fmaxf(fmaxf(fabsf(ee0), fabsf(ee1)),
                                fmaxf(fabsf(ee2), fabsf(ee3))), fabsf(ee4));
        if (nrm < 1e-30f) nrm = 1.0f;
        float inv = 1.0f / nrm;
        e0 = ee0 * inv; e1 = ee1 * inv; e2 = ee2 * inv; e3 = ee3 * inv; e4 = ee4 * inv;
    }
    return e0;
}

// ---------------------------------------------------------------------------
// Kernel 2: grid determinants -> per-block partial max/min; sub==0 also
//           computes the (vlist[t], tlist[t]) determinant as a sentinel item.
// ---------------------------------------------------------------------------
__global__ __launch_bounds__(256) void det_kernel(
    const float* __restrict__ vlist, const float* __restrict__ tlist,
    const float* __restrict__ d, const float* __restrict__ b,
    const float* __restrict__ Clist,
    const float* __restrict__ a_arr, const float* __restrict__ rho_arr,
    float* __restrict__ pmax, float* __restrict__ pmin,
    float* __restrict__ e00vals) {

    __shared__ LayerShared L;
    __shared__ float s_e00;
    __shared__ float smax[256], smin[256];

    int t   = blockIdx.x >> 2;   // BPT == 4
    int sub = blockIdx.x & 3;
    int tid = threadIdx.x;

    float tper  = tlist[t];
    float omega = fmaxf(TWO_PI_F / tper, 0.0001f);

    if (tid < NL) {
        float am = a_arr[tid];
        float bm = b[tid];
        float rm = rho_arr[tid];
        L.xka[tid] = omega / am;
        L.xkb[tid] = omega / bm;
        float tt = bm / omega;
        L.gammk[tid] = 2.0f * tt * tt;
        L.dm[tid]  = d[tid];
        L.rm[tid]  = rm;
        L.irm[tid] = 1.0f / rm;
        float r2 = rm * rm;
        L.rho2[tid]  = r2;
        L.irho2[tid] = 1.0f / r2;
    }
    __syncthreads();

    float lmax = -3.402823466e38f;
    float lmin =  3.402823466e38f;
    int limit = (sub == 0) ? (CPB + 1) : CPB;
    int base  = sub * CPB;

    for (int i = tid; i < limit; i += 256) {
        float cvel = (i < CPB) ? Clist[base + i] : vlist[t];
        float det  = det_eval(cvel, omega, L);
        if (i < CPB) {
            lmax = fmaxf(lmax, det);
            lmin = fminf(lmin, det);
        } else {
            s_e00 = det;   // exactly one thread hits this (i == CPB)
        }
    }

    smax[tid] = lmax;
    smin[tid] = lmin;
    __syncthreads();
    for (int s = 128; s > 0; s >>= 1) {
        if (tid < s) {
            smax[tid] = fmaxf(smax[tid], smax[tid + s]);
            smin[tid] = fminf(smin[tid], smin[tid + s]);
        }
        __syncthreads();
    }
    if (tid == 0) {
        pmax[t * BPT + sub] = smax[0];
        pmin[t * BPT + sub] = smin[0];
        if (sub == 0) e00vals[t] = s_e00;
    }
}

// ---------------------------------------------------------------------------
// Kernel 3: combine partials, misfit transform, damping term, final sum
// ---------------------------------------------------------------------------
__global__ __launch_bounds__(512) void finalize_kernel(
    const float* __restrict__ b,
    const float* __restrict__ pmax, const float* __restrict__ pmin,
    const float* __restrict__ e00vals, float* __restrict__ out) {

    int tid = threadIdx.x;
    float acc = 0.0f;

    if (tid < NOBS) {
        float mx = -3.402823466e38f, mn = 3.402823466e38f;
        #pragma unroll
        for (int s = 0; s < BPT; ++s) {
            mx = fmaxf(mx, pmax[tid * BPT + s]);
            mn = fminf(mn, pmin[tid * BPT + s]);
        }
        float rng  = mx - mn;
        float e00  = e00vals[tid] / rng;
        float term = exp2f(LOG2_0P1 * fabsf(e00)) - 1.0f;  // 0.1^|e00| - 1
        acc = fabsf(term) * (1.0f / (float)NOBS);
    }
    if (tid < NL) {
        float bi = b[tid];
        float lb;
        if (tid == 0)            lb = bi - b[1];
        else if (tid == NL - 1)  lb = bi - b[NL - 2];
        else                     lb = 2.0f * bi - b[tid - 1] - b[tid + 1];
        acc += fabsf(lb * (1.0f / (float)NL));   // DAMP = 1.0
    }

    __shared__ float s[512];
    s[tid] = acc;
    __syncthreads();
    for (int st = 256; st > 0; st >>= 1) {
        if (tid < st) s[tid] += s[tid + st];
        __syncthreads();
    }
    if (tid == 0) out[0] = s[0];
}

// ---------------------------------------------------------------------------
extern "C" void kernel_launch(void* const* d_in, const int* in_sizes, int n_in,
                              void* d_out, int out_size, void* d_ws, size_t ws_size,
                              hipStream_t stream) {
    const float* vlist = (const float*)d_in[0];
    const float* tlist = (const float*)d_in[1];
    const float* d     = (const float*)d_in[2];
    const float* b     = (const float*)d_in[3];
    const float* Clist = (const float*)d_in[4];
    float* out = (float*)d_out;

    float* ws      = (float*)d_ws;
    float* a_arr   = ws;            // 64
    float* rho_arr = ws + 64;       // 64
    float* pmax    = ws + 128;      // 1600
    float* pmin    = ws + 1728;     // 1600
    float* e00v    = ws + 3328;     // 400   (total 3728 floats ≈ 15 KB)

    prep_kernel<<<1, 64, 0, stream>>>(b, a_arr, rho_arr);
    det_kernel<<<NOBS * BPT, 256, 0, stream>>>(vlist, tlist, d, b, Clist,
                                               a_arr, rho_arr, pmax, pmin, e00v);
    finalize_kernel<<<1, 512, 0, stream>>>(b, pmax, pmin, e00v, out);
}

// Round 2
// 451.220 us; speedup vs baseline: 1.6554x; 1.6554x over previous
//
#include <hip/hip_runtime.h>
#include <math.h>

#define NL    64
#define NOBS  400
#define NC    3000
#define BPT   4            // blocks per T-observation
#define CPB   (NC / BPT)   // 750 C-values per block
#define TWO_PI_F   6.2831853071795864769f
#define INV_2PI_F  0.15915494309189535f
#define LOG2E_F    1.4426950408889634f
#define LOG2_0P1  -3.3219280948873623f

// ---- native HW transcendentals (all ~1 ulp, single v_* instruction) -------
__device__ __forceinline__ float fsin(float x)  { return __builtin_amdgcn_sinf(x * INV_2PI_F); }
__device__ __forceinline__ float fcos(float x)  { return __builtin_amdgcn_cosf(x * INV_2PI_F); }
__device__ __forceinline__ float fexp2(float x) { return __builtin_amdgcn_exp2f(x); }
__device__ __forceinline__ float frcp(float x)  { return __builtin_amdgcn_rcpf(x); }
__device__ __forceinline__ float fsqrt(float x) { return __builtin_amdgcn_sqrtf(x); }

// ---------------------------------------------------------------------------
// Kernel 1: Brocher relations  b -> (a, rho), stored to workspace
// ---------------------------------------------------------------------------
__global__ void prep_kernel(const float* __restrict__ b, float* __restrict__ a_out,
                            float* __restrict__ rho_out) {
    int i = threadIdx.x;
    if (i < NL) {
        float bb = b[i];
        float b2 = bb * bb, b3 = b2 * bb, b4 = b3 * bb;
        float a = 0.9409f + 2.0947f * bb - 0.8206f * b2 + 0.2683f * b3 - 0.0251f * b4;
        float a2 = a * a, a3 = a2 * a, a4 = a3 * a, a5 = a4 * a;
        float rho = 1.6612f * a - 0.4721f * a2 + 0.0671f * a3 - 0.0043f * a4 + 0.000106f * a5;
        a_out[i] = a;
        rho_out[i] = rho;
    }
}

// ---------------------------------------------------------------------------
// Per-layer block-uniform precomputed parameters (omega fixed per block)
// ---------------------------------------------------------------------------
struct LayerShared {
    float xka[NL];
    float xkb[NL];
    float gammk[NL];
    float dm[NL];
    float rm[NL];
    float irm[NL];
};

// Dunkin determinant evaluation for one (cvel, omega) pair.
__device__ __forceinline__ float det_eval(float cvel, float omega, const LayerShared& L) {
    float wvno  = omega * frcp(cvel);
    float wvno2 = wvno * wvno;
    float wvno4 = wvno2 * wvno2;
    float t2    = -2.0f * wvno2;

    // halfspace (layer NL-1)
    float xka = L.xka[NL - 1];
    float xkb = L.xkb[NL - 1];
    float ra  = fsqrt((wvno + xka) * fabsf(wvno - xka));
    float rb  = fsqrt((wvno + xkb) * fabsf(wvno - xkb));
    float gammk = L.gammk[NL - 1];
    float gam   = gammk * wvno2;
    float gamm1 = gam - 1.0f;
    float r     = L.rm[NL - 1];
    float rarb  = ra * rb;

    float e0 = r * r * (gamm1 * gamm1 - gam * gammk * rarb);
    float e1 = -r * ra;
    float e2 = r * (gamm1 - gammk * rarb);
    float e3 = r * rb;
    float e4 = wvno2 - rarb;

    for (int m = NL - 2; m >= 0; --m) {
        xka = L.xka[m];
        xkb = L.xkb[m];
        ra  = fsqrt((wvno + xka) * fabsf(wvno - xka));
        rb  = fsqrt((wvno + xkb) * fabsf(wvno - xkb));
        gammk = L.gammk[m];
        gam   = gammk * wvno2;
        float dm = L.dm[m];
        float p = ra * dm;
        float q = rb * dm;

        // ---- _var ----
        float ira = frcp((ra > 0.0f) ? ra : 1.0f);
        float irb = frcp((rb > 0.0f) ? rb : 1.0f);

        float sinp = fsin(p);
        float facp = (p < 16.0f) ? fexp2(-2.0f * LOG2E_F * p) : 0.0f;
        float sinp_e = 0.5f - 0.5f * facp;
        bool ltp = wvno < xka;
        bool eqp = wvno == xka;
        float pex  = (ltp || eqp) ? 0.0f : p;
        float cosp = ltp ? fcos(p) : (eqp ? 1.0f : 0.5f + 0.5f * facp);
        float w = ltp ? (sinp * ira) : (eqp ? dm : (sinp_e * ira));
        float x = ltp ? (-ra * sinp) : (eqp ? 0.0f : (ra * sinp_e));

        float sinq = fsin(q);
        float facq = (q < 16.0f) ? fexp2(-2.0f * LOG2E_F * q) : 0.0f;
        float sinq_e = 0.5f - 0.5f * facq;
        bool lts = wvno < xkb;
        bool eqs = wvno == xkb;
        float sex  = (lts || eqs) ? 0.0f : q;
        float cosq = lts ? fcos(q) : (eqs ? 1.0f : 0.5f + 0.5f * facq);
        float y = lts ? (sinq * irb) : (eqs ? dm : (sinq_e * irb));
        float z = lts ? (-rb * sinq) : (eqs ? 0.0f : (rb * sinq_e));

        float exa = pex + sex;
        float a0  = (exa < 60.0f) ? fexp2(-LOG2E_F * exa) : 0.0f;

        float cpcq = cosp * cosq;
        float cpy  = cosp * y,  cpz = cosp * z;
        float cqw  = cosq * w,  cqx = cosq * x;
        float xy = x * y, xz = x * z, wy = w * y, wz = w * z;

        // ---- ca entries ----
        float gamm1l = gam - 1.0f;
        float twgm1  = gam + gamm1l;
        float gmgmk  = gam * gammk;
        float gmgm1  = gam * gamm1l;
        float gm1sq  = gamm1l * gamm1l;
        float rm    = L.rm[m];
        float irm   = L.irm[m];
        float rho2  = rm * rm;
        float irho2 = irm * irm;
        float a0pq = a0 - cpcq;

        float c00 = cpcq - 2.0f * gmgm1 * a0pq - gmgmk * xz - wvno2 * gm1sq * wy;
        float c01 = (wvno2 * cpy - cqx) * irm;
        float c02 = -(twgm1 * a0pq + gammk * xz + wvno2 * gamm1l * wy) * irm;
        float c03 = (cpz - wvno2 * cqw) * irm;
        float c04 = -(2.0f * wvno2 * a0pq + xz + wvno4 * wy) * irho2;
        float c10 = (gmgmk * cpz - gm1sq * cqw) * rm;
        float c12 = gammk * cpz - gamm1l * cqw;
        float c30 = (gm1sq * cpy - gmgmk * cqx) * rm;
        float c32 = gamm1l * cpy - gammk * cqx;
        float c40 = -(2.0f * gmgmk * gm1sq * a0pq + gmgmk * gmgmk * xz + gm1sq * gm1sq * wy) * rho2;
        float c42 = -(gmgm1 * twgm1 * a0pq + gam * gammk * gammk * xz + gamm1l * gm1sq * wy) * rm;
        float c22 = a0 + 2.0f * (cpcq - c00);

        // row 2 of ca is t2 * {c42, c32, -, c12, c02} — fold t2 into e2 once.
        float e2t = e2 * t2;

        float ee0 = e0 * c00 + e1 * c10 + e2t * c42 + e3 * c30 + e4 * c40;
        float ee1 = e0 * c01 + e1 * cpcq + e2t * c32 - e3 * xy  + e4 * c30;
        float ee2 = e0 * c02 + e1 * c12  + e2 * c22 + e3 * c32 + e4 * c42;
        float ee3 = e0 * c03 - e1 * wz   + e2t * c12 + e3 * cpcq + e4 * c10;
        float ee4 = e0 * c04 + e1 * c03  + e2t * c02 + e3 * c01 + e4 * c00;

        float nrm = fmaxf(fmaxf(fmaxf(fabsf(ee0), fabsf(ee1)),
                                fmaxf(fabsf(ee2), fabsf(ee3))), fabsf(ee4));
        float inv = (nrm < 1e-30f) ? 1.0f : frcp(nrm);
        e0 = ee0 * inv; e1 = ee1 * inv; e2 = ee2 * inv; e3 = ee3 * inv; e4 = ee4 * inv;
    }
    return e0;
}

// ---------------------------------------------------------------------------
// Kernel 2: grid determinants -> per-block partial max/min; sub==0 also
//           computes the (vlist[t], tlist[t]) determinant as a sentinel item.
// ---------------------------------------------------------------------------
__global__ __launch_bounds__(256) void det_kernel(
    const float* __restrict__ vlist, const float* __restrict__ tlist,
    const float* __restrict__ d, const float* __restrict__ b,
    const float* __restrict__ Clist,
    const float* __restrict__ a_arr, const float* __restrict__ rho_arr,
    float* __restrict__ pmax, float* __restrict__ pmin,
    float* __restrict__ e00vals) {

    __shared__ LayerShared L;
    __shared__ float s_e00;
    __shared__ float smax[256], smin[256];

    int t   = blockIdx.x >> 2;   // BPT == 4
    int sub = blockIdx.x & 3;
    int tid = threadIdx.x;

    float tper  = tlist[t];
    float omega = fmaxf(TWO_PI_F / tper, 0.0001f);

    if (tid < NL) {
        float am = a_arr[tid];
        float bm = b[tid];
        float rm = rho_arr[tid];
        L.xka[tid] = omega / am;
        L.xkb[tid] = omega / bm;
        float tt = bm / omega;
        L.gammk[tid] = 2.0f * tt * tt;
        L.dm[tid]  = d[tid];
        L.rm[tid]  = rm;
        L.irm[tid] = 1.0f / rm;
    }
    __syncthreads();

    float lmax = -3.402823466e38f;
    float lmin =  3.402823466e38f;
    int limit = (sub == 0) ? (CPB + 1) : CPB;
    int base  = sub * CPB;

    for (int i = tid; i < limit; i += 256) {
        float cvel = (i < CPB) ? Clist[base + i] : vlist[t];
        float det  = det_eval(cvel, omega, L);
        if (i < CPB) {
            lmax = fmaxf(lmax, det);
            lmin = fminf(lmin, det);
        } else {
            s_e00 = det;   // exactly one thread hits this (i == CPB)
        }
    }

    smax[tid] = lmax;
    smin[tid] = lmin;
    __syncthreads();
    for (int s = 128; s > 0; s >>= 1) {
        if (tid < s) {
            smax[tid] = fmaxf(smax[tid], smax[tid + s]);
            smin[tid] = fminf(smin[tid], smin[tid + s]);
        }
        __syncthreads();
    }
    if (tid == 0) {
        pmax[t * BPT + sub] = smax[0];
        pmin[t * BPT + sub] = smin[0];
        if (sub == 0) e00vals[t] = s_e00;
    }
}

// ---------------------------------------------------------------------------
// Kernel 3: combine partials, misfit transform, damping term, final sum
// ---------------------------------------------------------------------------
__global__ __launch_bounds__(512) void finalize_kernel(
    const float* __restrict__ b,
    const float* __restrict__ pmax, const float* __restrict__ pmin,
    const float* __restrict__ e00vals, float* __restrict__ out) {

    int tid = threadIdx.x;
    float acc = 0.0f;

    if (tid < NOBS) {
        float mx = -3.402823466e38f, mn = 3.402823466e38f;
        #pragma unroll
        for (int s = 0; s < BPT; ++s) {
            mx = fmaxf(mx, pmax[tid * BPT + s]);
            mn = fminf(mn, pmin[tid * BPT + s]);
        }
        float rng  = mx - mn;
        float e00  = e00vals[tid] / rng;
        float term = exp2f(LOG2_0P1 * fabsf(e00)) - 1.0f;  // 0.1^|e00| - 1
        acc = fabsf(term) * (1.0f / (float)NOBS);
    }
    if (tid < NL) {
        float bi = b[tid];
        float lb;
        if (tid == 0)            lb = bi - b[1];
        else if (tid == NL - 1)  lb = bi - b[NL - 2];
        else                     lb = 2.0f * bi - b[tid - 1] - b[tid + 1];
        acc += fabsf(lb * (1.0f / (float)NL));   // DAMP = 1.0
    }

    __shared__ float s[512];
    s[tid] = acc;
    __syncthreads();
    for (int st = 256; st > 0; st >>= 1) {
        if (tid < st) s[tid] += s[tid + st];
        __syncthreads();
    }
    if (tid == 0) out[0] = s[0];
}

// ---------------------------------------------------------------------------
extern "C" void kernel_launch(void* const* d_in, const int* in_sizes, int n_in,
                              void* d_out, int out_size, void* d_ws, size_t ws_size,
                              hipStream_t stream) {
    const float* vlist = (const float*)d_in[0];
    const float* tlist = (const float*)d_in[1];
    const float* d     = (const float*)d_in[2];
    const float* b     = (const float*)d_in[3];
    const float* Clist = (const float*)d_in[4];
    float* out = (float*)d_out;

    float* ws      = (float*)d_ws;
    float* a_arr   = ws;            // 64
    float* rho_arr = ws + 64;       // 64
    float* pmax    = ws + 128;      // 1600
    float* pmin    = ws + 1728;     // 1600
    float* e00v    = ws + 3328;     // 400   (total 3728 floats ≈ 15 KB)

    prep_kernel<<<1, 64, 0, stream>>>(b, a_arr, rho_arr);
    det_kernel<<<NOBS * BPT, 256, 0, stream>>>(vlist, tlist, d, b, Clist,
                                               a_arr, rho_arr, pmax, pmin, e00v);
    finalize_kernel<<<1, 512, 0, stream>>>(b, pmax, pmin, e00v, out);
}